// Round 8
// baseline (26.606 us; speedup 1.0000x reference)
//
#include <hip/hip_runtime.h>

#define N 2048
#define NT 256
#define EL 8            // elements per thread
#define HEIGHTF 0.1f
#define PROMF 0.05f
#define MD1 9           // MINDIST-1: suppress |i-j| <= 9
#define LVLS 8          // sparse-table levels: windows 2,4,...,256

__global__ __launch_bounds__(NT)
void peak_kernel(const float* __restrict__ x, float* __restrict__ out) {
    __shared__ float xs[N];
    __shared__ float actl[16 + N + 24];       // act with -inf guards (pos p -> actl[16+p])
    __shared__ unsigned int nk32[3 + NT + 3]; // winner words, 3 guard words each side
    __shared__ float TMX[LVLS][N];            // TMX[k][i] = max xs[i, min(i+2^(k+1), N))
    __shared__ float TMN[LVLS][N];
    __shared__ float wred[8];
    __shared__ int wtot[4];
    __shared__ unsigned short klist[NT];
    __shared__ unsigned char keepres[N];
    __shared__ int scnt;
    __shared__ unsigned short spos[128];

    const int row = blockIdx.x;
    const int t = threadIdx.x;
    const int base = t * EL;
    const float* xr = x + row * (size_t)N;
    const int wv = t >> 6, ln = t & 63;

    // ---- 1. load + exact min/max + guards ----
    float4 Ld0 = ((const float4*)(xr + base))[0];
    float4 Ld1 = ((const float4*)(xr + base))[1];
    float v0[EL] = {Ld0.x, Ld0.y, Ld0.z, Ld0.w, Ld1.x, Ld1.y, Ld1.z, Ld1.w};
    float mn = v0[0], mx = v0[0];
    #pragma unroll
    for (int e = 1; e < EL; ++e) { mn = fminf(mn, v0[e]); mx = fmaxf(mx, v0[e]); }
    #pragma unroll
    for (int off = 32; off > 0; off >>= 1) {
        mn = fminf(mn, __shfl_xor(mn, off, 64));
        mx = fmaxf(mx, __shfl_xor(mx, off, 64));
    }
    if (ln == 0) { wred[wv] = mn; wred[4 + wv] = mx; }
    if (t == 0) {
        nk32[0] = 0; nk32[1] = 0; nk32[2] = 0;
        nk32[3+NT] = 0; nk32[3+NT+1] = 0; nk32[3+NT+2] = 0;
        scnt = 0;
    }
    if (t < 16) actl[t] = -1e30f;             // positions -16..-1
    if (t < 24) actl[16 + N + t] = -1e30f;    // positions N..N+23
    __syncthreads();

    // ---- 2. normalize (exact IEEE f32 division, matches reference) ----
    const float xmin = fminf(fminf(wred[0], wred[1]), fminf(wred[2], wred[3]));
    const float xmax = fmaxf(fmaxf(wred[4], wred[5]), fmaxf(wred[6], wred[7]));
    const float den = (xmax - xmin) + 1e-5f;
    float vn[EL];
    #pragma unroll
    for (int e = 0; e < EL; ++e) {
        vn[e] = (v0[e] - xmin) / den;
        xs[base + e] = vn[e];
    }
    __syncthreads();

    // ---- 3. candidates (strict local max & height) + level-0 tables ----
    unsigned int undec = 0, kept = 0;
    #pragma unroll
    for (int e = 0; e < EL; ++e) {
        int i = base + e;
        float v = vn[e];
        float lf = (e == 0) ? ((i >= 1) ? xs[i-1] : 3e38f) : vn[e-1];
        float rt = (e == EL-1) ? ((i+1 < N) ? xs[i+1] : 3e38f) : vn[e+1];
        bool c = (i >= 1) && (i <= N-2) && (v > lf) && (v > rt) && (v >= HEIGHTF);
        if (c) undec |= (1u << e);
        actl[16 + i] = c ? v : -1e30f;
    }
    #pragma unroll
    for (int j = 0; j < EL; ++j) {            // level 0: stride-NT, conflict-free
        int i = t + j * NT;
        float a0 = xs[i];
        bool inb = (i + 1 < N);
        float nb = inb ? xs[i + 1] : 0.0f;
        TMX[0][i] = fmaxf(a0, inb ? nb : -3e38f);
        TMN[0][i] = fminf(a0, inb ? nb : 3e38f);
    }
    __syncthreads();

    // ---- 4. gather register act window a[40] = positions [base-16, base+24) ----
    float a[40];
    {
        const float4* ap = (const float4*)(actl + base);  // actl[base] = pos base-16
        #pragma unroll
        for (int q = 0; q < 10; ++q) {
            float4 w = ap[q];
            a[4*q+0] = w.x; a[4*q+1] = w.y; a[4*q+2] = w.z; a[4*q+3] = w.w;
        }
    }

    auto compute_wins = [&](unsigned int ud) -> unsigned int {
        float m2v[25], m4v[23], m8v[19];
        #pragma unroll
        for (int s = 0; s < 25; ++s) m2v[s] = fmaxf(a[7+s], a[8+s]);
        #pragma unroll
        for (int s = 0; s < 23; ++s) m4v[s] = fmaxf(m2v[s], m2v[s+2]);
        #pragma unroll
        for (int s = 0; s < 19; ++s) m8v[s] = fmaxf(m4v[s], m4v[s+4]);
        unsigned int wb = 0;
        #pragma unroll
        for (int e = 0; e < EL; ++e) {
            if (ud & (1u << e)) {
                float v = a[16+e];
                float wl = fmaxf(m8v[e], a[15+e]);      // max act [i-9, i-1]
                float wr = fmaxf(m8v[10+e], a[25+e]);   // max act [i+1, i+9]
                if (wl < v && wr <= v) wb |= (1u << e); // left tie beats, right tie loses
            }
        }
        return wb;
    };

    unsigned int winb = undec ? compute_wins(undec) : 0u;
    unsigned int* nkp = nk32 + 3;
    int tb = 0;                               // table levels built inside the loop
    bool done = false;

    // ---- 5. suppression rounds (== scipy highest-first greedy) + serial tail ----
    for (int round = 1; round <= 2048; ++round) {
        nkp[t] = winb;
        int cnt = __syncthreads_count(undec != 0);   // barrier + tail trigger
        if (cnt == 0) break;
        // decide from winner window
        unsigned long long V = 0;
        #pragma unroll
        for (int q = 0; q < 7; ++q)
            V |= ((unsigned long long)(nkp[t - 3 + q] & 0xFFu)) << (8 * q);
        V <<= 1;
        if (__ballot(V != 0ULL)) {
            #pragma unroll
            for (int e = 0; e < EL; ++e) {
                if (undec & (1u << e)) {
                    unsigned int w19 = (unsigned int)((V >> (16 + e)) & 0x7FFFFULL);
                    if (w19 & (1u << 9)) { kept |= (1u << e); undec &= ~(1u << e); }
                    else if (w19)        { undec &= ~(1u << e); }
                }
            }
            #pragma unroll
            for (int s = 0; s < 40; ++s)
                if ((V >> s) & 0x7FFFFULL) a[s] = -1e30f;
        }
        // piggyback: build table level `round` (hidden behind round barriers)
        if (round < LVLS) {
            int h = 1 << round;
            #pragma unroll
            for (int j = 0; j < EL; ++j) {
                int i = t + j * NT;
                bool inb = (i + h < N);
                TMX[round][i] = fmaxf(TMX[round-1][i], inb ? TMX[round-1][i+h] : -3e38f);
                TMN[round][i] = fminf(TMN[round-1][i], inb ? TMN[round-1][i+h] : 3e38f);
            }
            tb = round;
        }
        // serial tail: few survivors -> resolve exactly with wave-0 greedy
        if (cnt <= 16) {
            #pragma unroll
            for (int e = 0; e < EL; ++e) {
                if (undec & (1u << e)) {
                    int s = atomicAdd(&scnt, 1);
                    if (s < 128) spos[s] = (unsigned short)(base + e);
                }
            }
            __syncthreads();                  // pushes + this round's V-reads done
            const int m = scnt;               // uniform
            nkp[t] = 0;                       // reuse as merge words (safe after barrier)
            __syncthreads();
            if (m > 0 && m <= 64) {
                if (t < 64) {                 // wave 0: sort + greedy resolve
                    unsigned long long key = 0ULL;
                    if (t < m) {
                        int p0 = spos[t];
                        key = ((unsigned long long)__float_as_uint(xs[p0]) << 32)
                            | (unsigned long long)(unsigned)(N - 1 - p0);
                    }
                    #pragma unroll
                    for (int k = 2; k <= 64; k <<= 1) {
                        #pragma unroll
                        for (int j = k >> 1; j > 0; j >>= 1) {
                            unsigned long long other = __shfl_xor(key, j, 64);
                            bool takeMax = (((ln & k) == 0) == ((ln & j) == 0));
                            bool gt = key > other;
                            key = (takeMax == gt) ? key : other;
                        }
                    }
                    int sp = (int)(N - 1 - (int)(unsigned)(key & 0xFFFFFFFFULL));
                    unsigned long long mask = __ballot(key != 0ULL);
                    bool iwon = false;
                    while (mask) {
                        int L = __builtin_ctzll(mask);
                        int lpos = __shfl(sp, L, 64);
                        if (ln == L) iwon = true;
                        unsigned long long nearm =
                            __ballot(sp >= lpos - MD1 && sp <= lpos + MD1);
                        mask &= ~nearm;
                    }
                    if (iwon) atomicOr(&nkp[sp >> 3], 1u << (sp & 7));
                }
            } else if (m > 64) {
                if (t == 0) scnt = 0;         // reset for a later attempt
            }
            __syncthreads();
            if (m == 0) done = true;
            else if (m <= 64) { kept |= nkp[t]; undec = 0; done = true; }
            if (done) break;
        }
        winb = (__ballot(undec != 0)) ? compute_wins(undec) : 0u;
    }

    // ---- 6. prefix compaction prep + finish any remaining table levels ----
    int myc = __popc(kept);
    int pre = myc;
    #pragma unroll
    for (int off = 1; off < 64; off <<= 1) {
        int up = __shfl_up(pre, off, 64);
        if (ln >= off) pre += up;
    }
    if (ln == 63) wtot[wv] = pre;
    #pragma unroll
    for (int e = 0; e < EL; ++e) keepres[base + e] = 0;
    for (int Lv = tb + 1; Lv < LVLS; ++Lv) {
        __syncthreads();
        int h = 1 << Lv;
        #pragma unroll
        for (int j = 0; j < EL; ++j) {
            int i = t + j * NT;
            bool inb = (i + h < N);
            TMX[Lv][i] = fmaxf(TMX[Lv-1][i], inb ? TMX[Lv-1][i+h] : -3e38f);
            TMN[Lv][i] = fminf(TMN[Lv-1][i], inb ? TMN[Lv-1][i+h] : 3e38f);
        }
    }
    __syncthreads();   // publish wtot/keepres/last level

    // ---- 6b. klist scatter ----
    {
        int woff = 0;
        #pragma unroll
        for (int w = 0; w < 4; ++w) woff += (w < wv) ? wtot[w] : 0;
        int slot = woff + pre - myc;
        #pragma unroll
        for (int e = 0; e < EL; ++e)
            if (kept & (1u << e)) klist[slot++] = (unsigned short)(base + e);
    }
    const int ktot = wtot[0] + wtot[1] + wtot[2] + wtot[3];
    __syncthreads();   // publish klist

    // ---- 7. prominence: one kept peak per thread (work-balanced) ----
    if (t < ktot) {
        const int i = klist[t];
        const float v = xs[i];
        float m = v;
        int p = i - 1;
        while (p >= 0) {                       // left base
            int len = p + 1;
            int k = (len >= (1 << LVLS)) ? LVLS : (31 - __clz(len));
            int s = p + 1 - (1 << k);
            float wmx = (k == 0) ? xs[s] : TMX[k-1][s];
            if (wmx > v) {
                while (k > 0) {
                    int half = 1 << (k - 1);
                    int rs = s + half;
                    float rm = (k == 1) ? xs[rs] : TMX[k-2][rs];
                    if (rm > v) s = rs;
                    else m = fminf(m, (k == 1) ? xs[rs] : TMN[k-2][rs]);
                    --k;
                }
                break;
            } else {
                m = fminf(m, (k == 0) ? xs[s] : TMN[k-1][s]);
                p = s - 1;
            }
        }
        const float lmin = m;
        m = v;
        p = i + 1;
        while (p < N) {                        // right base
            int len = N - p;
            int k = (len >= (1 << LVLS)) ? LVLS : (31 - __clz(len));
            float wmx = (k == 0) ? xs[p] : TMX[k-1][p];
            if (wmx > v) {
                while (k > 0) {
                    int half = 1 << (k - 1);
                    float lm = (k == 1) ? xs[p] : TMX[k-2][p];
                    if (!(lm > v)) {
                        m = fminf(m, (k == 1) ? xs[p] : TMN[k-2][p]);
                        p += half;
                    }
                    --k;
                }
                break;
            } else {
                m = fminf(m, (k == 0) ? xs[p] : TMN[k-1][p]);
                p += 1 << k;
            }
        }
        const float rmin = m;
        if (v - fmaxf(lmin, rmin) >= PROMF) keepres[i] = 1;
    }
    __syncthreads();

    // ---- 8. output ----
    float res[EL];
    #pragma unroll
    for (int e = 0; e < EL; ++e) res[e] = keepres[base + e] ? 1.0f : 0.0f;
    float* outr = out + row * (size_t)N + base;
    ((float4*)outr)[0] = make_float4(res[0], res[1], res[2], res[3]);
    ((float4*)outr)[1] = make_float4(res[4], res[5], res[6], res[7]);
}

extern "C" void kernel_launch(void* const* d_in, const int* in_sizes, int n_in,
                              void* d_out, int out_size, void* d_ws, size_t ws_size,
                              hipStream_t stream) {
    const float* x = (const float*)d_in[0];
    float* outp = (float*)d_out;
    const int rows = in_sizes[0] / N;
    peak_kernel<<<rows, NT, 0, stream>>>(x, outp);
}

// Round 9
// 23.239 us; speedup vs baseline: 1.1449x; 1.1449x over previous
//
#include <hip/hip_runtime.h>

#define N 2048
#define NT 256
#define EL 8            // elements per thread
#define HEIGHTF 0.1f
#define PROMF 0.05f
#define LVLS 8          // sparse-table levels: windows 2,4,...,256

__global__ __launch_bounds__(NT)
void peak_kernel(const float* __restrict__ x, float* __restrict__ out) {
    __shared__ float xs[N];
    __shared__ float actl[16 + N + 24];       // act with -inf guards (pos p -> actl[16+p])
    __shared__ unsigned int nk32[3 + NT + 3]; // CUMULATIVE kept masks, 3 guard words/side
    __shared__ float TMX[LVLS][N];            // TMX[k][i] = max xs[i, min(i+2^(k+1), N))
    __shared__ float TMN[LVLS][N];
    __shared__ float wred[8];
    __shared__ int wtot[4];
    __shared__ unsigned short klist[NT];
    __shared__ unsigned char keepres[N];
    __shared__ int donecnt;

    const int row = blockIdx.x;
    const int t = threadIdx.x;
    const int base = t * EL;
    const float* xr = x + row * (size_t)N;
    const int wv = t >> 6, ln = t & 63;

    // ---- 1. load + exact min/max + init ----
    float4 Ld0 = ((const float4*)(xr + base))[0];
    float4 Ld1 = ((const float4*)(xr + base))[1];
    float v0[EL] = {Ld0.x, Ld0.y, Ld0.z, Ld0.w, Ld1.x, Ld1.y, Ld1.z, Ld1.w};
    float mn = v0[0], mx = v0[0];
    #pragma unroll
    for (int e = 1; e < EL; ++e) { mn = fminf(mn, v0[e]); mx = fmaxf(mx, v0[e]); }
    #pragma unroll
    for (int off = 32; off > 0; off >>= 1) {
        mn = fminf(mn, __shfl_xor(mn, off, 64));
        mx = fmaxf(mx, __shfl_xor(mx, off, 64));
    }
    if (ln == 0) { wred[wv] = mn; wred[4 + wv] = mx; }
    nk32[t] = 0;                               // zero ALL publish words (async needs it)
    if (t < 6) nk32[NT + t] = 0;               // remaining words incl. guards
    if (t == 0) donecnt = 0;
    if (t < 16) actl[t] = -1e30f;              // positions -16..-1
    if (t < 24) actl[16 + N + t] = -1e30f;     // positions N..N+23
    __syncthreads();

    // ---- 2. normalize (exact IEEE f32 division, matches reference) ----
    const float xmin = fminf(fminf(wred[0], wred[1]), fminf(wred[2], wred[3]));
    const float xmax = fmaxf(fmaxf(wred[4], wred[5]), fmaxf(wred[6], wred[7]));
    const float den = (xmax - xmin) + 1e-5f;
    float vn[EL];
    #pragma unroll
    for (int e = 0; e < EL; ++e) {
        vn[e] = (v0[e] - xmin) / den;
        xs[base + e] = vn[e];
    }
    __syncthreads();

    // ---- 3. candidates (strict local max & height) ----
    unsigned int undec = 0, kept = 0;
    #pragma unroll
    for (int e = 0; e < EL; ++e) {
        int i = base + e;
        float v = vn[e];
        float lf = (e == 0) ? ((i >= 1) ? xs[i-1] : 3e38f) : vn[e-1];
        float rt = (e == EL-1) ? ((i+1 < N) ? xs[i+1] : 3e38f) : vn[e+1];
        bool c = (i >= 1) && (i <= N-2) && (v > lf) && (v > rt) && (v >= HEIGHTF);
        if (c) undec |= (1u << e);
        actl[16 + i] = c ? v : -1e30f;
    }
    __syncthreads();

    // ---- 4. register act window a[40] = positions [base-16, base+24) ----
    float a[40];
    {
        const float4* ap = (const float4*)(actl + base);  // actl[base] = pos base-16
        #pragma unroll
        for (int q = 0; q < 10; ++q) {
            float4 w = ap[q];
            a[4*q+0] = w.x; a[4*q+1] = w.y; a[4*q+2] = w.z; a[4*q+3] = w.w;
        }
    }

    auto compute_wins = [&](unsigned int ud) -> unsigned int {
        float m2v[25], m4v[23], m8v[19];
        #pragma unroll
        for (int s = 0; s < 25; ++s) m2v[s] = fmaxf(a[7+s], a[8+s]);
        #pragma unroll
        for (int s = 0; s < 23; ++s) m4v[s] = fmaxf(m2v[s], m2v[s+2]);
        #pragma unroll
        for (int s = 0; s < 19; ++s) m8v[s] = fmaxf(m4v[s], m4v[s+4]);
        unsigned int wb = 0;
        #pragma unroll
        for (int e = 0; e < EL; ++e) {
            if (ud & (1u << e)) {
                float v = a[16+e];
                float wl = fmaxf(m8v[e], a[15+e]);      // max act [i-9, i-1]
                float wr = fmaxf(m8v[10+e], a[25+e]);   // max act [i+1, i+9]
                if (wl < v && wr <= v) wb |= (1u << e); // left tie beats, right tie loses
            }
        }
        return wb;
    };

    // ---- 5. ASYNC barrier-free suppression (== scipy highest-first greedy).
    // Published words are CUMULATIVE kept masks -> monotone -> stale/mixed
    // reads are sound (clears+removals idempotent; local wins always valid). ----
    {
        volatile unsigned int* nkv = nk32 + 3;
        volatile int* dcp = (volatile int*)&donecnt;
        unsigned long long lastV = ~0ULL;
        bool counted = false;
        int guard = 0;
        while (true) {
            if (undec) {
                unsigned long long V = 0;
                #pragma unroll
                for (int q = 0; q < 7; ++q)
                    V |= ((unsigned long long)(nkv[t - 3 + q] & 0xFFu)) << (8 * q);
                V <<= 1;   // V bit b = winner at pos base + b - 25
                if (V != lastV) {
                    lastV = V;
                    #pragma unroll
                    for (int s = 0; s < 40; ++s)              // clear act near winners
                        if ((V >> s) & 0x7FFFFULL) a[s] = -1e30f;
                    #pragma unroll
                    for (int e = 0; e < EL; ++e)              // removals (self can't be set)
                        if (undec & (1u << e))
                            if ((V >> (16 + e)) & 0x7FFFFULL) undec &= ~(1u << e);
                    if (undec) {
                        unsigned int wb = compute_wins(undec);
                        if (wb) {
                            kept |= wb;
                            undec = 0;        // own winner suppresses all own elems (span<=7)
                            nkv[t] = kept;    // publish cumulative
                        }
                    }
                } else {
                    __builtin_amdgcn_s_sleep(1);   // waiting on neighbors
                }
            }
            if (!undec && !counted) {
                nkv[t] = kept;                 // final publish
                __threadfence_block();
                atomicAdd(&donecnt, 1);
                counted = true;
            }
            if (*dcp >= NT) break;
            if (counted) __builtin_amdgcn_s_sleep(2);
            if (++guard > 65536) break;        // safety net (never expected)
        }
    }
    __syncthreads();

    // ---- 6a. level-0 tables + kept prefix (ballot-free scan) + clear map ----
    float cx[EL], cn[EL];
    #pragma unroll
    for (int j = 0; j < EL; ++j) {
        int i = t + j * NT;
        float a0 = xs[i];
        bool inb = (i + 1 < N);
        float nb = inb ? xs[i + 1] : 0.0f;
        cx[j] = fmaxf(a0, inb ? nb : -3e38f);
        cn[j] = fminf(a0, inb ? nb : 3e38f);
        TMX[0][i] = cx[j];
        TMN[0][i] = cn[j];
    }
    int myc = __popc(kept);
    int pre = myc;
    #pragma unroll
    for (int off = 1; off < 64; off <<= 1) {
        int up = __shfl_up(pre, off, 64);
        if (ln >= off) pre += up;
    }
    if (ln == 63) wtot[wv] = pre;
    #pragma unroll
    for (int e = 0; e < EL; ++e) keepres[base + e] = 0;
    __syncthreads();

    // ---- 6b. klist scatter + dual-level table build (4 barriers total) ----
    {
        int woff = 0;
        #pragma unroll
        for (int w = 0; w < 4; ++w) woff += (w < wv) ? wtot[w] : 0;
        int slot = woff + pre - myc;
        #pragma unroll
        for (int e = 0; e < EL; ++e)
            if (kept & (1u << e)) klist[slot++] = (unsigned short)(base + e);
    }
    const int ktot = wtot[0] + wtot[1] + wtot[2] + wtot[3];
    #pragma unroll
    for (int pp = 0; pp < 3; ++pp) {               // pairs (1,2) (3,4) (5,6)
        const int Lv = 1 + 2 * pp;
        const int h = 1 << Lv;
        #pragma unroll
        for (int j = 0; j < EL; ++j) {
            int i = t + j * NT;
            float x1 = (i +   h < N) ? TMX[Lv-1][i+  h] : -3e38f;
            float x2 = (i + 2*h < N) ? TMX[Lv-1][i+2*h] : -3e38f;
            float x3 = (i + 3*h < N) ? TMX[Lv-1][i+3*h] : -3e38f;
            float n1 = (i +   h < N) ? TMN[Lv-1][i+  h] : 3e38f;
            float n2 = (i + 2*h < N) ? TMN[Lv-1][i+2*h] : 3e38f;
            float n3 = (i + 3*h < N) ? TMN[Lv-1][i+3*h] : 3e38f;
            float tx = fmaxf(cx[j], x1), tn = fminf(cn[j], n1);
            TMX[Lv][i] = tx;  TMN[Lv][i] = tn;
            cx[j] = fmaxf(tx, fmaxf(x2, x3));
            cn[j] = fminf(tn, fminf(n2, n3));
            TMX[Lv+1][i] = cx[j];  TMN[Lv+1][i] = cn[j];
        }
        __syncthreads();
    }
    {                                               // level 7
        const int h = 128;
        #pragma unroll
        for (int j = 0; j < EL; ++j) {
            int i = t + j * NT;
            float x1 = (i + h < N) ? TMX[6][i+h] : -3e38f;
            float n1 = (i + h < N) ? TMN[6][i+h] : 3e38f;
            cx[j] = fmaxf(cx[j], x1);
            cn[j] = fminf(cn[j], n1);
            TMX[7][i] = cx[j];  TMN[7][i] = cn[j];
        }
        __syncthreads();
    }

    // ---- 7. prominence: one peak/thread, L+R walks as 2 interleaved machines ----
    if (t < ktot) {
        const int i = klist[t];
        const float v = xs[i];
        const float* TX0 = &TMX[0][0];
        const float* TN0 = &TMN[0][0];
        // left machine
        int Lph = 0, Lp = i - 1, Lk = 0, Ls = 0;
        float Lm = v;
        if (Lp < 0) Lph = 2;
        // right machine
        int Rph = 0, Rp = i + 1, Rk = 0;
        float Rm = v;
        if (Rp >= N) Rph = 2;
        while (Lph != 2 || Rph != 2) {
            int lLev = 0, lIdx = 0, rLev = 0, rIdx = 0, Lrs = 0;
            if (Lph == 0) {
                int len = Lp + 1;
                Lk = (len >= (1 << LVLS)) ? LVLS : (31 - __clz(len));
                Ls = Lp + 1 - (1 << Lk);
                lLev = Lk - 1; lIdx = Ls;
            } else if (Lph == 1) {
                Lrs = Ls + (1 << (Lk - 1));
                lLev = Lk - 2; lIdx = Lrs;
            }
            if (Rph == 0) {
                int len = N - Rp;
                Rk = (len >= (1 << LVLS)) ? LVLS : (31 - __clz(len));
                rLev = Rk - 1; rIdx = Rp;
            } else if (Rph == 1) {
                rLev = Rk - 2; rIdx = Rp;
            }
            float lx = 0.0f, lnv = 0.0f, rx = 0.0f, rnv = 0.0f;
            if (Lph != 2) {   // both loads issue together (independent)
                const float* bX = (lLev < 0) ? xs : (TX0 + lLev * N);
                const float* bN = (lLev < 0) ? xs : (TN0 + lLev * N);
                lx = bX[lIdx]; lnv = bN[lIdx];
            }
            if (Rph != 2) {
                const float* bX = (rLev < 0) ? xs : (TX0 + rLev * N);
                const float* bN = (rLev < 0) ? xs : (TN0 + rLev * N);
                rx = bX[rIdx]; rnv = bN[rIdx];
            }
            if (Lph == 0) {
                if (lx > v) Lph = (Lk == 0) ? 2 : 1;
                else { Lm = fminf(Lm, lnv); Lp = Ls - 1; if (Lp < 0) Lph = 2; }
            } else if (Lph == 1) {
                if (lx > v) Ls = Lrs; else Lm = fminf(Lm, lnv);
                if (--Lk == 0) Lph = 2;
            }
            if (Rph == 0) {
                if (rx > v) Rph = (Rk == 0) ? 2 : 1;
                else { Rm = fminf(Rm, rnv); Rp += (1 << Rk); if (Rp >= N) Rph = 2; }
            } else if (Rph == 1) {
                if (!(rx > v)) { Rm = fminf(Rm, rnv); Rp += (1 << (Rk - 1)); }
                if (--Rk == 0) Rph = 2;
            }
        }
        if (v - fmaxf(Lm, Rm) >= PROMF) keepres[i] = 1;
    }
    __syncthreads();

    // ---- 8. output ----
    float res[EL];
    #pragma unroll
    for (int e = 0; e < EL; ++e) res[e] = keepres[base + e] ? 1.0f : 0.0f;
    float* outr = out + row * (size_t)N + base;
    ((float4*)outr)[0] = make_float4(res[0], res[1], res[2], res[3]);
    ((float4*)outr)[1] = make_float4(res[4], res[5], res[6], res[7]);
}

extern "C" void kernel_launch(void* const* d_in, const int* in_sizes, int n_in,
                              void* d_out, int out_size, void* d_ws, size_t ws_size,
                              hipStream_t stream) {
    const float* x = (const float*)d_in[0];
    float* outp = (float*)d_out;
    const int rows = in_sizes[0] / N;
    peak_kernel<<<rows, NT, 0, stream>>>(x, outp);
}